// Round 15
// baseline (481.838 us; speedup 1.0000x reference)
//
#include <hip/hip_runtime.h>
#include <hip/hip_bf16.h>

#define NN 100000
#define DD 128
#define RR 8
#define EE 100000
#define NP1 (NN + 1)
#define NB1 98            // ceil(NN/1024)
#define PADN (NB1 * 1024) // 100352, padded bins per relation
#define SEG 32            // targets per wave in preagg (100000/32 = 3125)
#define WPR (NN / SEG)    // 3125 waves per relation

typedef __attribute__((ext_vector_type(8))) short short8;
typedef __attribute__((ext_vector_type(4))) float f32x4;

__device__ __forceinline__ unsigned short f2bf(float v) {
  union { float f; unsigned int u; } x; x.f = v;
  unsigned int r = (x.u + 0x7FFFu + ((x.u >> 16) & 1u)) >> 16;
  return (unsigned short)r;
}

// ---- cast f32 -> bf16, 4 elems/thread, grid-stride
__global__ void k_cast4(const float* __restrict__ src, unsigned short* __restrict__ dst, int n4) {
  int i = blockIdx.x * blockDim.x + threadIdx.x;
  int stride = gridDim.x * blockDim.x;
  for (; i < n4; i += stride) {
    float4 v = reinterpret_cast<const float4*>(src)[i];
    ushort4 o;
    o.x = f2bf(v.x); o.y = f2bf(v.y); o.z = f2bf(v.z); o.w = f2bf(v.w);
    reinterpret_cast<ushort4*>(dst)[i] = o;
  }
}

// ---- cast + transpose 2 weight tensors: src[r][k][o] f32 -> dst[r][o][k] bf16
__global__ void k_castT2(const float* __restrict__ s1, unsigned short* __restrict__ d1,
                         const float* __restrict__ s2, unsigned short* __restrict__ d2,
                         int total) {
  int i = blockIdx.x * blockDim.x + threadIdx.x;
  if (i >= total) return;
  const float* src = blockIdx.y ? s2 : s1;
  unsigned short* dst = blockIdx.y ? d2 : d1;
  int r = i >> 14;
  int k = (i >> 7) & 127;
  int o = i & 127;
  dst[(r << 14) + (o << 7) + k] = f2bf(src[i]);
}

// zero two buffers in one launch
__global__ void k_zero2(unsigned int* __restrict__ p1, int n1,
                        unsigned int* __restrict__ p2, int n2) {
  int i = blockIdx.x * blockDim.x + threadIdx.x;
  if (i < n1) p1[i] = 0u;
  else if (i - n1 < n2) p2[i - n1] = 0u;
}

// ============== CSR build: counting sort of edges by target, per relation ======
__global__ void k_hist_mask(const int* __restrict__ edge_index, int* __restrict__ cnt,
                            unsigned int* __restrict__ mb) {
  int e = blockIdx.x * blockDim.x + threadIdx.x;
  int r = blockIdx.y;
  if (e >= EE) return;
  int tgt = edge_index[(size_t)r * 2 * EE + EE + e];
  atomicAdd(&cnt[r * PADN + tgt], 1);
  atomicOr(&mb[tgt], 1u << r);
}

__global__ void k_scan1(const int* __restrict__ cnt, int* __restrict__ start, int* __restrict__ bsum) {
  const int r = blockIdx.y, b = blockIdx.x, t = threadIdx.x;
  const int bin0 = b * 1024 + t * 4;
  int4 c = *reinterpret_cast<const int4*>(&cnt[r * PADN + bin0]);
  int s1 = c.x, s2 = s1 + c.y, s3 = s2 + c.z, tot = s3 + c.w;
  __shared__ int sh[256];
  sh[t] = tot;
  __syncthreads();
  for (int off = 1; off < 256; off <<= 1) {
    int v = (t >= off) ? sh[t - off] : 0;
    __syncthreads();
    sh[t] += v;
    __syncthreads();
  }
  int excl = sh[t] - tot;
  if (t == 255) bsum[r * NB1 + b] = sh[255];
  const int base = r * NP1;
  if (bin0 < NN) start[base + bin0] = excl;
  if (bin0 + 1 < NN) start[base + bin0 + 1] = excl + s1;
  if (bin0 + 2 < NN) start[base + bin0 + 2] = excl + s2;
  if (bin0 + 3 < NN) start[base + bin0 + 3] = excl + s3;
}

__global__ void k_scan2(const int* __restrict__ bsum, int* __restrict__ boff, int* __restrict__ start) {
  const int r = blockIdx.x, t = threadIdx.x;
  int v = (t < NB1) ? bsum[r * NB1 + t] : 0;
  __shared__ int sh[128];
  sh[t] = v;
  __syncthreads();
  for (int off = 1; off < 128; off <<= 1) {
    int u = (t >= off) ? sh[t - off] : 0;
    __syncthreads();
    sh[t] += u;
    __syncthreads();
  }
  if (t < NB1) boff[r * NB1 + t] = sh[t] - v;
  if (t == 0) start[r * NP1 + NN] = EE;
}

__global__ void k_scan3(int* __restrict__ start, const int* __restrict__ boff, int* __restrict__ cursor) {
  const int r = blockIdx.y, b = blockIdx.x, t = threadIdx.x;
  const int bin0 = b * 1024 + t * 4;
  const int off = boff[r * NB1 + b];
  const int base = r * NP1;
#pragma unroll
  for (int k = 0; k < 4; ++k) {
    int bin = bin0 + k;
    if (bin < NN) {
      int v = start[base + bin] + off;
      start[base + bin] = v;
      cursor[r * NN + bin] = v;
    }
  }
}

__global__ void k_scatter2(const int* __restrict__ edge_index, const float* __restrict__ ew,
                           int* __restrict__ cursor, int2* __restrict__ es) {
  int e = blockIdx.x * blockDim.x + threadIdx.x;
  int r = blockIdx.y;
  if (e >= EE) return;
  const int* src_p = edge_index + (size_t)r * 2 * EE;
  int tgt = src_p[EE + e];
  int pos = atomicAdd(&cursor[r * NN + tgt], 1);
  es[(size_t)r * EE + pos] = make_int2(src_p[e], __float_as_int(ew[(size_t)r * EE + e]));
}

// ============== pre-aggregation (register window + v_readlane broadcast) ======
// One wave handles SEG=32 consecutive targets (mean window 32 edges; one
// coalesced int2 load caches it, P(window>64) ~ 1e-8 with fallback). Per round
// up to 32 INDEPENDENT X-row gathers issue back-to-back. Boundaries in SGPRs
// via readlane; slot-active test is a scalar branch.

__device__ __forceinline__ void preagg_wave(const unsigned short* __restrict__ Xsrc,
                                            const int2* __restrict__ es,
                                            const int* __restrict__ start,
                                            int r, int n0, int lane,
                                            float (&a0)[SEG], float (&a1)[SEG]) {
  const size_t rEE = (size_t)r * EE;
  int b = start[r * NP1 + n0 + (lane < SEG ? lane : SEG)];
  int p[SEG + 1];
#pragma unroll
  for (int i = 0; i <= SEG; ++i) p[i] = __builtin_amdgcn_readlane(b, i);
#pragma unroll
  for (int i = 0; i < SEG; ++i) { a0[i] = 0.f; a1[i] = 0.f; }
  const int p0 = p[0];
  const int count = p[SEG] - p0;
  if (count <= 0) return;
  int rounds = 0;
#pragma unroll
  for (int i = 0; i < SEG; ++i) rounds = max(rounds, p[i + 1] - p[i]);
  const unsigned int* Xu = reinterpret_cast<const unsigned int*>(Xsrc);

  if (count <= 64) {
    int wl = lane < count ? lane : count - 1;
    int2 ew = es[rEE + p0 + wl];
    int esrc = ew.x;
    int ewbits = ew.y;
    for (int j = 0; j < rounds; ++j) {
#pragma unroll
      for (int i = 0; i < SEG; ++i) {
        int pos = p[i] + j;
        if (pos < p[i + 1]) {              // scalar compare, wave-uniform branch
          int widx = pos - p0;             // wave-uniform lane index
          int s = __builtin_amdgcn_readlane(esrc, widx);
          float wv = __int_as_float(__builtin_amdgcn_readlane(ewbits, widx));
          unsigned int d = Xu[(size_t)s * 64 + lane];
          union { unsigned int u; float f; } lo, hi;
          lo.u = d << 16;
          hi.u = d & 0xFFFF0000u;
          a0[i] += wv * lo.f;
          a1[i] += wv * hi.f;
        }
      }
    }
  } else {
    // rare fallback: window larger than 64 edges — direct vector loads
    for (int j = 0; j < rounds; ++j) {
#pragma unroll
      for (int i = 0; i < SEG; ++i) {
        int pos = p[i] + j;
        if (pos < p[i + 1]) {
          int2 e = es[rEE + pos];
          float wv = __int_as_float(e.y);
          unsigned int d = Xu[(size_t)e.x * 64 + lane];
          union { unsigned int u; float f; } lo, hi;
          lo.u = d << 16;
          hi.u = d & 0xFFFF0000u;
          a0[i] += wv * lo.f;
          a1[i] += wv * hi.f;
        }
      }
    }
  }
}

__launch_bounds__(256, 4)
__global__ void k_preagg_seg3(const unsigned short* __restrict__ Xsrc,
                              const int2* __restrict__ es, const int* __restrict__ start,
                              unsigned short* __restrict__ P0, unsigned short* __restrict__ P1,
                              unsigned short* __restrict__ P2,
                              int rbase, int nrel) {
  const int wid = blockIdx.x * 4 + (threadIdx.x >> 6);
  if (wid >= nrel * WPR) return;
  const int lane = threadIdx.x & 63;
  const int rr = wid / WPR;
  const int n0 = (wid - rr * WPR) * SEG;
  float a0[SEG], a1[SEG];
  preagg_wave(Xsrc, es, start, rbase + rr, n0, lane, a0, a1);
  unsigned short* P = (rr == 0) ? P0 : ((rr == 1) ? P1 : P2);
  unsigned int* Pw = reinterpret_cast<unsigned int*>(P);
#pragma unroll
  for (int i = 0; i < SEG; ++i)
    Pw[(size_t)(n0 + i) * 64 + lane] = (unsigned int)f2bf(a0[i]) | ((unsigned int)f2bf(a1[i]) << 16);
}

__launch_bounds__(256, 4)
__global__ void k_preagg_seg8(const unsigned short* __restrict__ Xsrc,
                              const int2* __restrict__ es, const int* __restrict__ start,
                              unsigned short* __restrict__ P0, unsigned short* __restrict__ Pws) {
  const int wid = blockIdx.x * 4 + (threadIdx.x >> 6);
  if (wid >= RR * WPR) return;
  const int lane = threadIdx.x & 63;
  const int rr = wid / WPR;
  const int n0 = (wid - rr * WPR) * SEG;
  float a0[SEG], a1[SEG];
  preagg_wave(Xsrc, es, start, rr, n0, lane, a0, a1);
  unsigned short* P = (rr == 0) ? P0 : (Pws + (size_t)(rr - 1) * NN * DD);
  unsigned int* Pw = reinterpret_cast<unsigned int*>(P);
#pragma unroll
  for (int i = 0; i < SEG; ++i)
    Pw[(size_t)(n0 + i) * 64 + lane] = (unsigned int)f2bf(a0[i]) | ((unsigned int)f2bf(a1[i]) << 16);
}

// ================= GEMM machinery (R11, best-known) =================
// Staging via global_load_lds width=16. LDS dest LINEAR; chunk-XOR swizzle
// applied to the GLOBAL source chunk index (involution); swizzled reads below.

typedef const __attribute__((address_space(1))) void* gas1_t;
typedef __attribute__((address_space(3))) void* las3_t;

__device__ __forceinline__ void gl16(const void* g, void* s) {
  __builtin_amdgcn_global_load_lds((gas1_t)g, (las3_t)s, 16, 0, 0);
}

// stage a 128x128 bf16 tile; lane covers row rowblk+(l>>4), slot l&15
template <bool CLAMP>
__device__ __forceinline__ void stage_lds(const unsigned short* __restrict__ g,
                                          unsigned short* lds, int t, int row0) {
  const int w = t >> 6, l = t & 63;
  const int sub = l >> 4, s = l & 15;
#pragma unroll
  for (int c = 0; c < 8; ++c) {
    int rowblk = c * 16 + w * 4;          // wave-uniform (4 rows / wave / iter)
    int row = rowblk + sub;
    int grow = row0 + row;
    int sr = CLAMP ? (grow < NN ? grow : NN - 1) : grow;
    const unsigned short* src = g + (size_t)sr * 128 + ((s ^ (row & 7)) << 3);
    gl16(src, lds + rowblk * 128);
  }
}

__device__ __forceinline__ void mfma_tile(const unsigned short* __restrict__ lA,
                                          const unsigned short* __restrict__ lB,
                                          f32x4 (&acc)[2][8], int w, int l) {
  const int lrow = l & 15, kgrp = l >> 4;
#pragma unroll
  for (int ks = 0; ks < 4; ++ks) {
    int kc = ks * 4 + kgrp;
    int ra = w * 32 + lrow;
    int rb = ra + 16;
    short8 a0 = *reinterpret_cast<const short8*>(&lA[(ra << 7) + ((kc ^ (ra & 7)) << 3)]);
    short8 a1 = *reinterpret_cast<const short8*>(&lA[(rb << 7) + ((kc ^ (rb & 7)) << 3)]);
#pragma unroll
    for (int ct = 0; ct < 8; ++ct) {
      int ro = ct * 16 + lrow;
      short8 b = *reinterpret_cast<const short8*>(&lB[(ro << 7) + ((kc ^ (ro & 7)) << 3)]);
      acc[0][ct] = __builtin_amdgcn_mfma_f32_16x16x32_bf16(a0, b, acc[0][ct], 0, 0, 0);
      acc[1][ct] = __builtin_amdgcn_mfma_f32_16x16x32_bf16(a1, b, acc[1][ct], 0, 0, 0);
    }
  }
}

// -------- tier-A fused per-layer GEMM: self + 8 P-terms + mask*bias --------
template <bool L1>
__launch_bounds__(256, 2)
__global__ void k_gemm_fused(const unsigned short* __restrict__ Aself,
                             const unsigned short* __restrict__ Wself,
                             const unsigned short* __restrict__ P0,
                             const unsigned short* __restrict__ Pws,
                             const unsigned short* __restrict__ Wrel,
                             const unsigned int* __restrict__ maskbits,
                             const float* __restrict__ bias,
                             void* __restrict__ outp) {
  __shared__ __align__(16) unsigned short lA[128 * 128];
  __shared__ __align__(16) unsigned short lB[128 * 128];
  const int t = threadIdx.x;
  const int row0 = blockIdx.x * 128;
  const int w = t >> 6, l = t & 63;
  const int lrow = l & 15, kgrp = l >> 4;
  f32x4 acc[2][8] = {};

  stage_lds<true>(Aself, lA, t, row0);
  stage_lds<false>(Wself, lB, t, 0);
  __syncthreads();
  mfma_tile(lA, lB, acc, w, l);
#pragma unroll 1
  for (int r = 0; r < RR; ++r) {
    const unsigned short* Pr = (r == 0) ? P0 : (Pws + (size_t)(r - 1) * NN * DD);
    __syncthreads();
    stage_lds<true>(Pr, lA, t, row0);
    stage_lds<false>(Wrel + (r << 14), lB, t, 0);
    __syncthreads();
    mfma_tile(lA, lB, acc, w, l);
  }

  // mask @ bias, synthesized in registers (k-slice 0..7, kgrp==0 only)
  {
    short8 a0 = {}, a1 = {}, bf[8];
#pragma unroll
    for (int ct = 0; ct < 8; ++ct) bf[ct] = short8{};
    if (kgrp == 0) {
      int ra = row0 + w * 32 + lrow;
      int rb = ra + 16;
      unsigned int ma = (ra < NN) ? maskbits[ra] : 0u;
      unsigned int mb = (rb < NN) ? maskbits[rb] : 0u;
#pragma unroll
      for (int k = 0; k < 8; ++k) {
        a0[k] = (short)(((ma >> k) & 1u) ? 0x3F80 : 0);
        a1[k] = (short)(((mb >> k) & 1u) ? 0x3F80 : 0);
      }
#pragma unroll
      for (int ct = 0; ct < 8; ++ct) {
        int o = ct * 16 + lrow;
#pragma unroll
        for (int k = 0; k < 8; ++k) bf[ct][k] = (short)f2bf(bias[k * 128 + o]);
      }
    }
#pragma unroll
    for (int ct = 0; ct < 8; ++ct) {
      acc[0][ct] = __builtin_amdgcn_mfma_f32_16x16x32_bf16(a0, bf[ct], acc[0][ct], 0, 0, 0);
      acc[1][ct] = __builtin_amdgcn_mfma_f32_16x16x32_bf16(a1, bf[ct], acc[1][ct], 0, 0, 0);
    }
  }

#pragma unroll
  for (int rt = 0; rt < 2; ++rt) {
#pragma unroll
    for (int j = 0; j < 4; ++j) {
      int grow = row0 + w * 32 + rt * 16 + kgrp * 4 + j;
      if (grow < NN) {
        if (L1) {
          unsigned short* op = (unsigned short*)outp + (size_t)grow * 128 + lrow;
#pragma unroll
          for (int ct = 0; ct < 8; ++ct) op[ct * 16] = f2bf(fmaxf(acc[rt][ct][j], 0.f));
        } else {
          float* op = (float*)outp + (size_t)grow * 128 + lrow;
#pragma unroll
          for (int ct = 0; ct < 8; ++ct) op[ct * 16] = acc[rt][ct][j];
        }
      }
    }
  }
}

// -------- tier-B multi-term GEMM --------
template <int NT>
__launch_bounds__(256, 2)
__global__ void k_gemm_multi(const unsigned short* __restrict__ A0, const unsigned short* __restrict__ W0,
                             const unsigned short* __restrict__ A1, const unsigned short* __restrict__ W1,
                             const unsigned short* __restrict__ A2, const unsigned short* __restrict__ W2,
                             const unsigned short* __restrict__ A3, const unsigned short* __restrict__ W3,
                             float* __restrict__ outp, int accum) {
  __shared__ __align__(16) unsigned short lA[128 * 128];
  __shared__ __align__(16) unsigned short lB[128 * 128];
  const int t = threadIdx.x;
  const int row0 = blockIdx.x * 128;
  const int w = t >> 6, l = t & 63;
  const int lrow = l & 15, kgrp = l >> 4;
  f32x4 acc[2][8] = {};

  const unsigned short* As[4] = {A0, A1, A2, A3};
  const unsigned short* Ws[4] = {W0, W1, W2, W3};
#pragma unroll
  for (int term = 0; term < NT; ++term) {
    if (term) __syncthreads();
    stage_lds<true>(As[term], lA, t, row0);
    stage_lds<false>(Ws[term], lB, t, 0);
    __syncthreads();
    mfma_tile(lA, lB, acc, w, l);
  }

#pragma unroll
  for (int rt = 0; rt < 2; ++rt) {
#pragma unroll
    for (int j = 0; j < 4; ++j) {
      int grow = row0 + w * 32 + rt * 16 + kgrp * 4 + j;
      if (grow < NN) {
        float* op = outp + (size_t)grow * 128 + lrow;
        if (accum) {
#pragma unroll
          for (int ct = 0; ct < 8; ++ct) op[ct * 16] += acc[rt][ct][j];
        } else {
#pragma unroll
          for (int ct = 0; ct < 8; ++ct) op[ct * 16] = acc[rt][ct][j];
        }
      }
    }
  }
}

// tier-B epilogue layer1
__global__ void k_epi1(const float* __restrict__ h32, const unsigned int* __restrict__ maskbits,
                       const float* __restrict__ bias, unsigned short* __restrict__ hb) {
  int gid = blockIdx.x * blockDim.x + threadIdx.x;
  if (gid >= NN * 32) return;
  int n = gid >> 5, c = (gid & 31) << 2;
  float4 v = *reinterpret_cast<const float4*>(h32 + (size_t)n * 128 + c);
  unsigned int mb = maskbits[n];
  float b0 = 0, b1 = 0, b2 = 0, b3 = 0;
#pragma unroll
  for (int r = 0; r < RR; ++r) {
    if ((mb >> r) & 1u) {
      const float* bp = bias + r * 128 + c;
      b0 += bp[0]; b1 += bp[1]; b2 += bp[2]; b3 += bp[3];
    }
  }
  ushort4 o;
  o.x = f2bf(fmaxf(v.x + b0, 0.f));
  o.y = f2bf(fmaxf(v.y + b1, 0.f));
  o.z = f2bf(fmaxf(v.z + b2, 0.f));
  o.w = f2bf(fmaxf(v.w + b3, 0.f));
  *reinterpret_cast<ushort4*>(hb + (size_t)n * 128 + c) = o;
}

// tier-B epilogue layer2
__global__ void k_epi2(float* __restrict__ out, const unsigned int* __restrict__ maskbits,
                       const float* __restrict__ bias) {
  int gid = blockIdx.x * blockDim.x + threadIdx.x;
  if (gid >= NN * 32) return;
  int n = gid >> 5, c = (gid & 31) << 2;
  unsigned int mb = maskbits[n];
  if (!mb) return;
  float b0 = 0, b1 = 0, b2 = 0, b3 = 0;
#pragma unroll
  for (int r = 0; r < RR; ++r) {
    if ((mb >> r) & 1u) {
      const float* bp = bias + r * 128 + c;
      b0 += bp[0]; b1 += bp[1]; b2 += bp[2]; b3 += bp[3];
    }
  }
  float* p = out + (size_t)n * 128 + c;
  float4 v = *reinterpret_cast<const float4*>(p);
  v.x += b0; v.y += b1; v.z += b2; v.w += b3;
  *reinterpret_cast<float4*>(p) = v;
}

extern "C" void kernel_launch(void* const* d_in, const int* in_sizes, int n_in,
                              void* d_out, int out_size, void* d_ws, size_t ws_size,
                              hipStream_t stream) {
  const float* X   = (const float*)d_in[0];
  const int*   EI  = (const int*)d_in[1];
  const float* EW  = (const float*)d_in[2];
  const float* rW1 = (const float*)d_in[3];
  const float* sW1 = (const float*)d_in[4];
  const float* b1  = (const float*)d_in[5];
  const float* rW2 = (const float*)d_in[6];
  const float* sW2 = (const float*)d_in[7];
  const float* b2  = (const float*)d_in[8];
  float* out = (float*)d_out;
  char* ws = (char*)d_ws;

  size_t off = 0;
  auto take = [&](size_t sz) { char* p = ws + off; off += (sz + 255) & ~(size_t)255; return p; };
  unsigned short* Xb   = (unsigned short*)take((size_t)NN * DD * 2);
  unsigned short* hb   = (unsigned short*)take((size_t)NN * DD * 2);
  unsigned int*  maskb = (unsigned int*)take((size_t)NN * 4);
  unsigned short* rW1t = (unsigned short*)take((size_t)RR * DD * DD * 2);
  unsigned short* sW1t = (unsigned short*)take((size_t)DD * DD * 2);
  unsigned short* rW2t = (unsigned short*)take((size_t)RR * DD * DD * 2);
  unsigned short* sW2t = (unsigned short*)take((size_t)DD * DD * 2);
  int*   cnt    = (int*)take((size_t)RR * PADN * 4);
  int*   start  = (int*)take((size_t)RR * NP1 * 4);
  int*   cursor = (int*)take((size_t)RR * NN * 4);
  int*   bsum   = (int*)take((size_t)RR * NB1 * 4);
  int*   boff   = (int*)take((size_t)RR * NB1 * 4);
  int2*  es     = (int2*)take((size_t)RR * EE * 8);

  const size_t szReg = ((size_t)NN * DD * 2 + 255) & ~(size_t)255;
  const bool bigA = (off + 7 * szReg <= ws_size);
  unsigned short* Pws = nullptr;
  float* h32 = nullptr;
  if (bigA) {
    Pws = (unsigned short*)take(7 * szReg);   // P regions r=1..7
  } else {
    h32 = (float*)take((size_t)NN * DD * 4);
  }

  // casts
  k_cast4<<<2048, 256, 0, stream>>>(X, Xb, NN * DD / 4);
  k_castT2<<<dim3((RR * DD * DD + 255) / 256, 2), 256, 0, stream>>>(rW1, rW1t, rW2, rW2t, RR * DD * DD);
  k_castT2<<<dim3((DD * DD + 255) / 256, 2), 256, 0, stream>>>(sW1, sW1t, sW2, sW2t, DD * DD);

  // CSR build + mask bits
  k_zero2<<<(NN + RR * PADN + 255) / 256, 256, 0, stream>>>(maskb, NN, (unsigned int*)cnt, RR * PADN);
  k_hist_mask<<<dim3((EE + 255) / 256, RR), 256, 0, stream>>>(EI, cnt, maskb);
  k_scan1<<<dim3(NB1, RR), 256, 0, stream>>>(cnt, start, bsum);
  k_scan2<<<RR, 128, 0, stream>>>(bsum, boff, start);
  k_scan3<<<dim3(NB1, RR), 256, 0, stream>>>(start, boff, cursor);
  k_scatter2<<<dim3((EE + 255) / 256, RR), 256, 0, stream>>>(EI, EW, cursor, es);

  const int nblk = (NN + 127) / 128;  // 782
  unsigned short* outu = (unsigned short*)d_out;

  if (bigA) {
    const int pblk = (RR * WPR + 3) / 4;
    // ---- layer 1: P0 -> d_out (scratch), r1..r7 -> Pws.
    k_preagg_seg8<<<pblk, 256, 0, stream>>>(Xb, es, start, outu, Pws);
    k_gemm_fused<true><<<nblk, 256, 0, stream>>>(Xb, sW1t, outu, Pws, rW1t, maskb, b1, hb);
    // ---- layer 2: P0 -> Xb (layer-1 input dead), r1..r7 -> Pws.
    k_preagg_seg8<<<pblk, 256, 0, stream>>>(hb, es, start, Xb, Pws);
    k_gemm_fused<false><<<nblk, 256, 0, stream>>>(hb, sW2t, Xb, Pws, rW2t, maskb, b2, out);
  } else {
    unsigned short* h32u = (unsigned short*)h32;
    const int pblk3 = (3 * WPR + 3) / 4;
    const int pblk2 = (2 * WPR + 3) / 4;
    {
      unsigned short* P0 = outu;
      unsigned short* P1 = outu + (size_t)NN * DD;
      unsigned short* P2 = hb;
      k_preagg_seg3<<<pblk3, 256, 0, stream>>>(Xb, es, start, P0, P1, P2, 0, 3);
      k_gemm_multi<4><<<nblk, 256, 0, stream>>>(Xb, sW1t, P0, rW1t, P1, rW1t + (1 << 14), P2, rW1t + (2 << 14), h32, 0);
      k_preagg_seg3<<<pblk3, 256, 0, stream>>>(Xb, es, start, P0, P1, P2, 3, 3);
      k_gemm_multi<3><<<nblk, 256, 0, stream>>>(P0, rW1t + (3 << 14), P1, rW1t + (4 << 14), P2, rW1t + (5 << 14), nullptr, nullptr, h32, 1);
      k_preagg_seg3<<<pblk2, 256, 0, stream>>>(Xb, es, start, P0, P1, P2, 6, 2);
      k_gemm_multi<2><<<nblk, 256, 0, stream>>>(P0, rW1t + (6 << 14), P1, rW1t + (7 << 14), nullptr, nullptr, nullptr, nullptr, h32, 1);
    }
    k_epi1<<<(NN * 32 + 255) / 256, 256, 0, stream>>>(h32, maskb, b1, hb);
    {
      unsigned short* P0 = h32u;
      unsigned short* P1 = h32u + (size_t)NN * DD;
      unsigned short* P2 = Xb;
      k_preagg_seg3<<<pblk3, 256, 0, stream>>>(hb, es, start, P0, P1, P2, 0, 3);
      k_gemm_multi<4><<<nblk, 256, 0, stream>>>(hb, sW2t, P0, rW2t, P1, rW2t + (1 << 14), P2, rW2t + (2 << 14), out, 0);
      k_preagg_seg3<<<pblk3, 256, 0, stream>>>(hb, es, start, P0, P1, P2, 3, 3);
      k_gemm_multi<3><<<nblk, 256, 0, stream>>>(P0, rW2t + (3 << 14), P1, rW2t + (4 << 14), P2, rW2t + (5 << 14), nullptr, nullptr, out, 1);
      k_preagg_seg3<<<pblk2, 256, 0, stream>>>(hb, es, start, P0, P1, P2, 6, 2);
      k_gemm_multi<2><<<nblk, 256, 0, stream>>>(P0, rW2t + (6 << 14), P1, rW2t + (7 << 14), nullptr, nullptr, nullptr, nullptr, out, 1);
    }
    k_epi2<<<(NN * 32 + 255) / 256, 256, 0, stream>>>(out, maskb, b2);
  }
}

// Round 16
// 404.288 us; speedup vs baseline: 1.1918x; 1.1918x over previous
//
#include <hip/hip_runtime.h>
#include <hip/hip_bf16.h>

#define NN 100000
#define DD 128
#define RR 8
#define EE 100000
#define NP1 (NN + 1)
#define NB1 98            // ceil(NN/1024)
#define PADN (NB1 * 1024) // 100352, padded bins per relation
#define SEG 16            // targets per wave in preagg (measured optimum)
#define WPR (NN / SEG)    // 6250 waves per relation

typedef __attribute__((ext_vector_type(8))) short short8;
typedef __attribute__((ext_vector_type(4))) float f32x4;

__device__ __forceinline__ unsigned short f2bf(float v) {
  union { float f; unsigned int u; } x; x.f = v;
  unsigned int r = (x.u + 0x7FFFu + ((x.u >> 16) & 1u)) >> 16;
  return (unsigned short)r;
}

// ---- cast f32 -> bf16, 4 elems/thread, grid-stride
__global__ void k_cast4(const float* __restrict__ src, unsigned short* __restrict__ dst, int n4) {
  int i = blockIdx.x * blockDim.x + threadIdx.x;
  int stride = gridDim.x * blockDim.x;
  for (; i < n4; i += stride) {
    float4 v = reinterpret_cast<const float4*>(src)[i];
    ushort4 o;
    o.x = f2bf(v.x); o.y = f2bf(v.y); o.z = f2bf(v.z); o.w = f2bf(v.w);
    reinterpret_cast<ushort4*>(dst)[i] = o;
  }
}

// ---- cast + transpose 2 weight tensors: src[r][k][o] f32 -> dst[r][o][k] bf16
__global__ void k_castT2(const float* __restrict__ s1, unsigned short* __restrict__ d1,
                         const float* __restrict__ s2, unsigned short* __restrict__ d2,
                         int total) {
  int i = blockIdx.x * blockDim.x + threadIdx.x;
  if (i >= total) return;
  const float* src = blockIdx.y ? s2 : s1;
  unsigned short* dst = blockIdx.y ? d2 : d1;
  int r = i >> 14;
  int k = (i >> 7) & 127;
  int o = i & 127;
  dst[(r << 14) + (o << 7) + k] = f2bf(src[i]);
}

// zero two buffers in one launch
__global__ void k_zero2(unsigned int* __restrict__ p1, int n1,
                        unsigned int* __restrict__ p2, int n2) {
  int i = blockIdx.x * blockDim.x + threadIdx.x;
  if (i < n1) p1[i] = 0u;
  else if (i - n1 < n2) p2[i - n1] = 0u;
}

// ============== CSR build: counting sort of edges by target, per relation ======
__global__ void k_hist_mask(const int* __restrict__ edge_index, int* __restrict__ cnt,
                            unsigned int* __restrict__ mb) {
  int e = blockIdx.x * blockDim.x + threadIdx.x;
  int r = blockIdx.y;
  if (e >= EE) return;
  int tgt = edge_index[(size_t)r * 2 * EE + EE + e];
  atomicAdd(&cnt[r * PADN + tgt], 1);
  atomicOr(&mb[tgt], 1u << r);
}

__global__ void k_scan1(const int* __restrict__ cnt, int* __restrict__ start, int* __restrict__ bsum) {
  const int r = blockIdx.y, b = blockIdx.x, t = threadIdx.x;
  const int bin0 = b * 1024 + t * 4;
  int4 c = *reinterpret_cast<const int4*>(&cnt[r * PADN + bin0]);
  int s1 = c.x, s2 = s1 + c.y, s3 = s2 + c.z, tot = s3 + c.w;
  __shared__ int sh[256];
  sh[t] = tot;
  __syncthreads();
  for (int off = 1; off < 256; off <<= 1) {
    int v = (t >= off) ? sh[t - off] : 0;
    __syncthreads();
    sh[t] += v;
    __syncthreads();
  }
  int excl = sh[t] - tot;
  if (t == 255) bsum[r * NB1 + b] = sh[255];
  const int base = r * NP1;
  if (bin0 < NN) start[base + bin0] = excl;
  if (bin0 + 1 < NN) start[base + bin0 + 1] = excl + s1;
  if (bin0 + 2 < NN) start[base + bin0 + 2] = excl + s2;
  if (bin0 + 3 < NN) start[base + bin0 + 3] = excl + s3;
}

__global__ void k_scan2(const int* __restrict__ bsum, int* __restrict__ boff, int* __restrict__ start) {
  const int r = blockIdx.x, t = threadIdx.x;
  int v = (t < NB1) ? bsum[r * NB1 + t] : 0;
  __shared__ int sh[128];
  sh[t] = v;
  __syncthreads();
  for (int off = 1; off < 128; off <<= 1) {
    int u = (t >= off) ? sh[t - off] : 0;
    __syncthreads();
    sh[t] += u;
    __syncthreads();
  }
  if (t < NB1) boff[r * NB1 + t] = sh[t] - v;
  if (t == 0) start[r * NP1 + NN] = EE;
}

__global__ void k_scan3(int* __restrict__ start, const int* __restrict__ boff, int* __restrict__ cursor) {
  const int r = blockIdx.y, b = blockIdx.x, t = threadIdx.x;
  const int bin0 = b * 1024 + t * 4;
  const int off = boff[r * NB1 + b];
  const int base = r * NP1;
#pragma unroll
  for (int k = 0; k < 4; ++k) {
    int bin = bin0 + k;
    if (bin < NN) {
      int v = start[base + bin] + off;
      start[base + bin] = v;
      cursor[r * NN + bin] = v;
    }
  }
}

__global__ void k_scatter2(const int* __restrict__ edge_index, const float* __restrict__ ew,
                           int* __restrict__ cursor, int2* __restrict__ es) {
  int e = blockIdx.x * blockDim.x + threadIdx.x;
  int r = blockIdx.y;
  if (e >= EE) return;
  const int* src_p = edge_index + (size_t)r * 2 * EE;
  int tgt = src_p[EE + e];
  int pos = atomicAdd(&cursor[r * NN + tgt], 1);
  es[(size_t)r * EE + pos] = make_int2(src_p[e], __float_as_int(ew[(size_t)r * EE + e]));
}

// ============== pre-aggregation (register window + v_readlane broadcast) ======
// One wave handles SEG=16 consecutive targets (mean window 16 edges; one
// coalesced int2 load caches it). Per round up to 16 INDEPENDENT X-row gathers
// issue back-to-back. Boundaries in SGPRs via readlane; slot-active test is a
// scalar branch. launch_bounds(256,8): 8 waves/EU for max latency-hiding TLP.

__device__ __forceinline__ void preagg_wave(const unsigned short* __restrict__ Xsrc,
                                            const int2* __restrict__ es,
                                            const int* __restrict__ start,
                                            int r, int n0, int lane,
                                            float (&a0)[SEG], float (&a1)[SEG]) {
  const size_t rEE = (size_t)r * EE;
  int b = start[r * NP1 + n0 + (lane < SEG ? lane : SEG)];
  int p[SEG + 1];
#pragma unroll
  for (int i = 0; i <= SEG; ++i) p[i] = __builtin_amdgcn_readlane(b, i);
#pragma unroll
  for (int i = 0; i < SEG; ++i) { a0[i] = 0.f; a1[i] = 0.f; }
  const int p0 = p[0];
  const int count = p[SEG] - p0;
  if (count <= 0) return;
  int rounds = 0;
#pragma unroll
  for (int i = 0; i < SEG; ++i) rounds = max(rounds, p[i + 1] - p[i]);
  const unsigned int* Xu = reinterpret_cast<const unsigned int*>(Xsrc);

  if (count <= 64) {
    int wl = lane < count ? lane : count - 1;
    int2 ew = es[rEE + p0 + wl];
    int esrc = ew.x;
    int ewbits = ew.y;
    for (int j = 0; j < rounds; ++j) {
#pragma unroll
      for (int i = 0; i < SEG; ++i) {
        int pos = p[i] + j;
        if (pos < p[i + 1]) {              // scalar compare, wave-uniform branch
          int widx = pos - p0;             // wave-uniform lane index
          int s = __builtin_amdgcn_readlane(esrc, widx);
          float wv = __int_as_float(__builtin_amdgcn_readlane(ewbits, widx));
          unsigned int d = Xu[(size_t)s * 64 + lane];
          union { unsigned int u; float f; } lo, hi;
          lo.u = d << 16;
          hi.u = d & 0xFFFF0000u;
          a0[i] += wv * lo.f;
          a1[i] += wv * hi.f;
        }
      }
    }
  } else {
    // rare fallback: window larger than 64 edges — direct vector loads
    for (int j = 0; j < rounds; ++j) {
#pragma unroll
      for (int i = 0; i < SEG; ++i) {
        int pos = p[i] + j;
        if (pos < p[i + 1]) {
          int2 e = es[rEE + pos];
          float wv = __int_as_float(e.y);
          unsigned int d = Xu[(size_t)e.x * 64 + lane];
          union { unsigned int u; float f; } lo, hi;
          lo.u = d << 16;
          hi.u = d & 0xFFFF0000u;
          a0[i] += wv * lo.f;
          a1[i] += wv * hi.f;
        }
      }
    }
  }
}

__launch_bounds__(256, 8)
__global__ void k_preagg_seg3(const unsigned short* __restrict__ Xsrc,
                              const int2* __restrict__ es, const int* __restrict__ start,
                              unsigned short* __restrict__ P0, unsigned short* __restrict__ P1,
                              unsigned short* __restrict__ P2,
                              int rbase, int nrel) {
  const int wid = blockIdx.x * 4 + (threadIdx.x >> 6);
  if (wid >= nrel * WPR) return;
  const int lane = threadIdx.x & 63;
  const int rr = wid / WPR;
  const int n0 = (wid - rr * WPR) * SEG;
  float a0[SEG], a1[SEG];
  preagg_wave(Xsrc, es, start, rbase + rr, n0, lane, a0, a1);
  unsigned short* P = (rr == 0) ? P0 : ((rr == 1) ? P1 : P2);
  unsigned int* Pw = reinterpret_cast<unsigned int*>(P);
#pragma unroll
  for (int i = 0; i < SEG; ++i)
    Pw[(size_t)(n0 + i) * 64 + lane] = (unsigned int)f2bf(a0[i]) | ((unsigned int)f2bf(a1[i]) << 16);
}

__launch_bounds__(256, 8)
__global__ void k_preagg_seg8(const unsigned short* __restrict__ Xsrc,
                              const int2* __restrict__ es, const int* __restrict__ start,
                              unsigned short* __restrict__ P0, unsigned short* __restrict__ Pws) {
  const int wid = blockIdx.x * 4 + (threadIdx.x >> 6);
  if (wid >= RR * WPR) return;
  const int lane = threadIdx.x & 63;
  const int rr = wid / WPR;
  const int n0 = (wid - rr * WPR) * SEG;
  float a0[SEG], a1[SEG];
  preagg_wave(Xsrc, es, start, rr, n0, lane, a0, a1);
  unsigned short* P = (rr == 0) ? P0 : (Pws + (size_t)(rr - 1) * NN * DD);
  unsigned int* Pw = reinterpret_cast<unsigned int*>(P);
#pragma unroll
  for (int i = 0; i < SEG; ++i)
    Pw[(size_t)(n0 + i) * 64 + lane] = (unsigned int)f2bf(a0[i]) | ((unsigned int)f2bf(a1[i]) << 16);
}

// ================= GEMM machinery (R11, best-known) =================
// Staging via global_load_lds width=16. LDS dest LINEAR; chunk-XOR swizzle
// applied to the GLOBAL source chunk index (involution); swizzled reads below.

typedef const __attribute__((address_space(1))) void* gas1_t;
typedef __attribute__((address_space(3))) void* las3_t;

__device__ __forceinline__ void gl16(const void* g, void* s) {
  __builtin_amdgcn_global_load_lds((gas1_t)g, (las3_t)s, 16, 0, 0);
}

// stage a 128x128 bf16 tile; lane covers row rowblk+(l>>4), slot l&15
template <bool CLAMP>
__device__ __forceinline__ void stage_lds(const unsigned short* __restrict__ g,
                                          unsigned short* lds, int t, int row0) {
  const int w = t >> 6, l = t & 63;
  const int sub = l >> 4, s = l & 15;
#pragma unroll
  for (int c = 0; c < 8; ++c) {
    int rowblk = c * 16 + w * 4;          // wave-uniform (4 rows / wave / iter)
    int row = rowblk + sub;
    int grow = row0 + row;
    int sr = CLAMP ? (grow < NN ? grow : NN - 1) : grow;
    const unsigned short* src = g + (size_t)sr * 128 + ((s ^ (row & 7)) << 3);
    gl16(src, lds + rowblk * 128);
  }
}

__device__ __forceinline__ void mfma_tile(const unsigned short* __restrict__ lA,
                                          const unsigned short* __restrict__ lB,
                                          f32x4 (&acc)[2][8], int w, int l) {
  const int lrow = l & 15, kgrp = l >> 4;
#pragma unroll
  for (int ks = 0; ks < 4; ++ks) {
    int kc = ks * 4 + kgrp;
    int ra = w * 32 + lrow;
    int rb = ra + 16;
    short8 a0 = *reinterpret_cast<const short8*>(&lA[(ra << 7) + ((kc ^ (ra & 7)) << 3)]);
    short8 a1 = *reinterpret_cast<const short8*>(&lA[(rb << 7) + ((kc ^ (rb & 7)) << 3)]);
#pragma unroll
    for (int ct = 0; ct < 8; ++ct) {
      int ro = ct * 16 + lrow;
      short8 b = *reinterpret_cast<const short8*>(&lB[(ro << 7) + ((kc ^ (ro & 7)) << 3)]);
      acc[0][ct] = __builtin_amdgcn_mfma_f32_16x16x32_bf16(a0, b, acc[0][ct], 0, 0, 0);
      acc[1][ct] = __builtin_amdgcn_mfma_f32_16x16x32_bf16(a1, b, acc[1][ct], 0, 0, 0);
    }
  }
}

// -------- tier-A fused per-layer GEMM: self + 8 P-terms + mask*bias --------
template <bool L1>
__launch_bounds__(256, 2)
__global__ void k_gemm_fused(const unsigned short* __restrict__ Aself,
                             const unsigned short* __restrict__ Wself,
                             const unsigned short* __restrict__ P0,
                             const unsigned short* __restrict__ Pws,
                             const unsigned short* __restrict__ Wrel,
                             const unsigned int* __restrict__ maskbits,
                             const float* __restrict__ bias,
                             void* __restrict__ outp) {
  __shared__ __align__(16) unsigned short lA[128 * 128];
  __shared__ __align__(16) unsigned short lB[128 * 128];
  const int t = threadIdx.x;
  const int row0 = blockIdx.x * 128;
  const int w = t >> 6, l = t & 63;
  const int lrow = l & 15, kgrp = l >> 4;
  f32x4 acc[2][8] = {};

  stage_lds<true>(Aself, lA, t, row0);
  stage_lds<false>(Wself, lB, t, 0);
  __syncthreads();
  mfma_tile(lA, lB, acc, w, l);
#pragma unroll 1
  for (int r = 0; r < RR; ++r) {
    const unsigned short* Pr = (r == 0) ? P0 : (Pws + (size_t)(r - 1) * NN * DD);
    __syncthreads();
    stage_lds<true>(Pr, lA, t, row0);
    stage_lds<false>(Wrel + (r << 14), lB, t, 0);
    __syncthreads();
    mfma_tile(lA, lB, acc, w, l);
  }

  // mask @ bias, synthesized in registers (k-slice 0..7, kgrp==0 only)
  {
    short8 a0 = {}, a1 = {}, bf[8];
#pragma unroll
    for (int ct = 0; ct < 8; ++ct) bf[ct] = short8{};
    if (kgrp == 0) {
      int ra = row0 + w * 32 + lrow;
      int rb = ra + 16;
      unsigned int ma = (ra < NN) ? maskbits[ra] : 0u;
      unsigned int mb = (rb < NN) ? maskbits[rb] : 0u;
#pragma unroll
      for (int k = 0; k < 8; ++k) {
        a0[k] = (short)(((ma >> k) & 1u) ? 0x3F80 : 0);
        a1[k] = (short)(((mb >> k) & 1u) ? 0x3F80 : 0);
      }
#pragma unroll
      for (int ct = 0; ct < 8; ++ct) {
        int o = ct * 16 + lrow;
#pragma unroll
        for (int k = 0; k < 8; ++k) bf[ct][k] = (short)f2bf(bias[k * 128 + o]);
      }
    }
#pragma unroll
    for (int ct = 0; ct < 8; ++ct) {
      acc[0][ct] = __builtin_amdgcn_mfma_f32_16x16x32_bf16(a0, bf[ct], acc[0][ct], 0, 0, 0);
      acc[1][ct] = __builtin_amdgcn_mfma_f32_16x16x32_bf16(a1, bf[ct], acc[1][ct], 0, 0, 0);
    }
  }

#pragma unroll
  for (int rt = 0; rt < 2; ++rt) {
#pragma unroll
    for (int j = 0; j < 4; ++j) {
      int grow = row0 + w * 32 + rt * 16 + kgrp * 4 + j;
      if (grow < NN) {
        if (L1) {
          unsigned short* op = (unsigned short*)outp + (size_t)grow * 128 + lrow;
#pragma unroll
          for (int ct = 0; ct < 8; ++ct) op[ct * 16] = f2bf(fmaxf(acc[rt][ct][j], 0.f));
        } else {
          float* op = (float*)outp + (size_t)grow * 128 + lrow;
#pragma unroll
          for (int ct = 0; ct < 8; ++ct) op[ct * 16] = acc[rt][ct][j];
        }
      }
    }
  }
}

// -------- tier-B multi-term GEMM --------
template <int NT>
__launch_bounds__(256, 2)
__global__ void k_gemm_multi(const unsigned short* __restrict__ A0, const unsigned short* __restrict__ W0,
                             const unsigned short* __restrict__ A1, const unsigned short* __restrict__ W1,
                             const unsigned short* __restrict__ A2, const unsigned short* __restrict__ W2,
                             const unsigned short* __restrict__ A3, const unsigned short* __restrict__ W3,
                             float* __restrict__ outp, int accum) {
  __shared__ __align__(16) unsigned short lA[128 * 128];
  __shared__ __align__(16) unsigned short lB[128 * 128];
  const int t = threadIdx.x;
  const int row0 = blockIdx.x * 128;
  const int w = t >> 6, l = t & 63;
  const int lrow = l & 15, kgrp = l >> 4;
  f32x4 acc[2][8] = {};

  const unsigned short* As[4] = {A0, A1, A2, A3};
  const unsigned short* Ws[4] = {W0, W1, W2, W3};
#pragma unroll
  for (int term = 0; term < NT; ++term) {
    if (term) __syncthreads();
    stage_lds<true>(As[term], lA, t, row0);
    stage_lds<false>(Ws[term], lB, t, 0);
    __syncthreads();
    mfma_tile(lA, lB, acc, w, l);
  }

#pragma unroll
  for (int rt = 0; rt < 2; ++rt) {
#pragma unroll
    for (int j = 0; j < 4; ++j) {
      int grow = row0 + w * 32 + rt * 16 + kgrp * 4 + j;
      if (grow < NN) {
        float* op = outp + (size_t)grow * 128 + lrow;
        if (accum) {
#pragma unroll
          for (int ct = 0; ct < 8; ++ct) op[ct * 16] += acc[rt][ct][j];
        } else {
#pragma unroll
          for (int ct = 0; ct < 8; ++ct) op[ct * 16] = acc[rt][ct][j];
        }
      }
    }
  }
}

// tier-B epilogue layer1
__global__ void k_epi1(const float* __restrict__ h32, const unsigned int* __restrict__ maskbits,
                       const float* __restrict__ bias, unsigned short* __restrict__ hb) {
  int gid = blockIdx.x * blockDim.x + threadIdx.x;
  if (gid >= NN * 32) return;
  int n = gid >> 5, c = (gid & 31) << 2;
  float4 v = *reinterpret_cast<const float4*>(h32 + (size_t)n * 128 + c);
  unsigned int mb = maskbits[n];
  float b0 = 0, b1 = 0, b2 = 0, b3 = 0;
#pragma unroll
  for (int r = 0; r < RR; ++r) {
    if ((mb >> r) & 1u) {
      const float* bp = bias + r * 128 + c;
      b0 += bp[0]; b1 += bp[1]; b2 += bp[2]; b3 += bp[3];
    }
  }
  ushort4 o;
  o.x = f2bf(fmaxf(v.x + b0, 0.f));
  o.y = f2bf(fmaxf(v.y + b1, 0.f));
  o.z = f2bf(fmaxf(v.z + b2, 0.f));
  o.w = f2bf(fmaxf(v.w + b3, 0.f));
  *reinterpret_cast<ushort4*>(hb + (size_t)n * 128 + c) = o;
}

// tier-B epilogue layer2
__global__ void k_epi2(float* __restrict__ out, const unsigned int* __restrict__ maskbits,
                       const float* __restrict__ bias) {
  int gid = blockIdx.x * blockDim.x + threadIdx.x;
  if (gid >= NN * 32) return;
  int n = gid >> 5, c = (gid & 31) << 2;
  unsigned int mb = maskbits[n];
  if (!mb) return;
  float b0 = 0, b1 = 0, b2 = 0, b3 = 0;
#pragma unroll
  for (int r = 0; r < RR; ++r) {
    if ((mb >> r) & 1u) {
      const float* bp = bias + r * 128 + c;
      b0 += bp[0]; b1 += bp[1]; b2 += bp[2]; b3 += bp[3];
    }
  }
  float* p = out + (size_t)n * 128 + c;
  float4 v = *reinterpret_cast<const float4*>(p);
  v.x += b0; v.y += b1; v.z += b2; v.w += b3;
  *reinterpret_cast<float4*>(p) = v;
}

extern "C" void kernel_launch(void* const* d_in, const int* in_sizes, int n_in,
                              void* d_out, int out_size, void* d_ws, size_t ws_size,
                              hipStream_t stream) {
  const float* X   = (const float*)d_in[0];
  const int*   EI  = (const int*)d_in[1];
  const float* EW  = (const float*)d_in[2];
  const float* rW1 = (const float*)d_in[3];
  const float* sW1 = (const float*)d_in[4];
  const float* b1  = (const float*)d_in[5];
  const float* rW2 = (const float*)d_in[6];
  const float* sW2 = (const float*)d_in[7];
  const float* b2  = (const float*)d_in[8];
  float* out = (float*)d_out;
  char* ws = (char*)d_ws;

  size_t off = 0;
  auto take = [&](size_t sz) { char* p = ws + off; off += (sz + 255) & ~(size_t)255; return p; };
  unsigned short* Xb   = (unsigned short*)take((size_t)NN * DD * 2);
  unsigned short* hb   = (unsigned short*)take((size_t)NN * DD * 2);
  unsigned int*  maskb = (unsigned int*)take((size_t)NN * 4);
  unsigned short* rW1t = (unsigned short*)take((size_t)RR * DD * DD * 2);
  unsigned short* sW1t = (unsigned short*)take((size_t)DD * DD * 2);
  unsigned short* rW2t = (unsigned short*)take((size_t)RR * DD * DD * 2);
  unsigned short* sW2t = (unsigned short*)take((size_t)DD * DD * 2);
  int*   cnt    = (int*)take((size_t)RR * PADN * 4);
  int*   start  = (int*)take((size_t)RR * NP1 * 4);
  int*   cursor = (int*)take((size_t)RR * NN * 4);
  int*   bsum   = (int*)take((size_t)RR * NB1 * 4);
  int*   boff   = (int*)take((size_t)RR * NB1 * 4);
  int2*  es     = (int2*)take((size_t)RR * EE * 8);

  const size_t szReg = ((size_t)NN * DD * 2 + 255) & ~(size_t)255;
  const bool bigA = (off + 7 * szReg <= ws_size);
  unsigned short* Pws = nullptr;
  float* h32 = nullptr;
  if (bigA) {
    Pws = (unsigned short*)take(7 * szReg);   // P regions r=1..7
  } else {
    h32 = (float*)take((size_t)NN * DD * 4);
  }

  // casts
  k_cast4<<<2048, 256, 0, stream>>>(X, Xb, NN * DD / 4);
  k_castT2<<<dim3((RR * DD * DD + 255) / 256, 2), 256, 0, stream>>>(rW1, rW1t, rW2, rW2t, RR * DD * DD);
  k_castT2<<<dim3((DD * DD + 255) / 256, 2), 256, 0, stream>>>(sW1, sW1t, sW2, sW2t, DD * DD);

  // CSR build + mask bits
  k_zero2<<<(NN + RR * PADN + 255) / 256, 256, 0, stream>>>(maskb, NN, (unsigned int*)cnt, RR * PADN);
  k_hist_mask<<<dim3((EE + 255) / 256, RR), 256, 0, stream>>>(EI, cnt, maskb);
  k_scan1<<<dim3(NB1, RR), 256, 0, stream>>>(cnt, start, bsum);
  k_scan2<<<RR, 128, 0, stream>>>(bsum, boff, start);
  k_scan3<<<dim3(NB1, RR), 256, 0, stream>>>(start, boff, cursor);
  k_scatter2<<<dim3((EE + 255) / 256, RR), 256, 0, stream>>>(EI, EW, cursor, es);

  const int nblk = (NN + 127) / 128;  // 782
  unsigned short* outu = (unsigned short*)d_out;

  if (bigA) {
    const int pblk = (RR * WPR + 3) / 4;
    // ---- layer 1: P0 -> d_out (scratch), r1..r7 -> Pws.
    k_preagg_seg8<<<pblk, 256, 0, stream>>>(Xb, es, start, outu, Pws);
    k_gemm_fused<true><<<nblk, 256, 0, stream>>>(Xb, sW1t, outu, Pws, rW1t, maskb, b1, hb);
    // ---- layer 2: P0 -> Xb (layer-1 input dead), r1..r7 -> Pws.
    k_preagg_seg8<<<pblk, 256, 0, stream>>>(hb, es, start, Xb, Pws);
    k_gemm_fused<false><<<nblk, 256, 0, stream>>>(hb, sW2t, Xb, Pws, rW2t, maskb, b2, out);
  } else {
    unsigned short* h32u = (unsigned short*)h32;
    const int pblk3 = (3 * WPR + 3) / 4;
    const int pblk2 = (2 * WPR + 3) / 4;
    {
      unsigned short* P0 = outu;
      unsigned short* P1 = outu + (size_t)NN * DD;
      unsigned short* P2 = hb;
      k_preagg_seg3<<<pblk3, 256, 0, stream>>>(Xb, es, start, P0, P1, P2, 0, 3);
      k_gemm_multi<4><<<nblk, 256, 0, stream>>>(Xb, sW1t, P0, rW1t, P1, rW1t + (1 << 14), P2, rW1t + (2 << 14), h32, 0);
      k_preagg_seg3<<<pblk3, 256, 0, stream>>>(Xb, es, start, P0, P1, P2, 3, 3);
      k_gemm_multi<3><<<nblk, 256, 0, stream>>>(P0, rW1t + (3 << 14), P1, rW1t + (4 << 14), P2, rW1t + (5 << 14), nullptr, nullptr, h32, 1);
      k_preagg_seg3<<<pblk2, 256, 0, stream>>>(Xb, es, start, P0, P1, P2, 6, 2);
      k_gemm_multi<2><<<nblk, 256, 0, stream>>>(P0, rW1t + (6 << 14), P1, rW1t + (7 << 14), nullptr, nullptr, nullptr, nullptr, h32, 1);
    }
    k_epi1<<<(NN * 32 + 255) / 256, 256, 0, stream>>>(h32, maskb, b1, hb);
    {
      unsigned short* P0 = h32u;
      unsigned short* P1 = h32u + (size_t)NN * DD;
      unsigned short* P2 = Xb;
      k_preagg_seg3<<<pblk3, 256, 0, stream>>>(hb, es, start, P0, P1, P2, 0, 3);
      k_gemm_multi<4><<<nblk, 256, 0, stream>>>(hb, sW2t, P0, rW2t, P1, rW2t + (1 << 14), P2, rW2t + (2 << 14), out, 0);
      k_preagg_seg3<<<pblk3, 256, 0, stream>>>(hb, es, start, P0, P1, P2, 3, 3);
      k_gemm_multi<3><<<nblk, 256, 0, stream>>>(P0, rW2t + (3 << 14), P1, rW2t + (4 << 14), P2, rW2t + (5 << 14), nullptr, nullptr, out, 1);
      k_preagg_seg3<<<pblk2, 256, 0, stream>>>(hb, es, start, P0, P1, P2, 6, 2);
      k_gemm_multi<2><<<nblk, 256, 0, stream>>>(P0, rW2t + (6 << 14), P1, rW2t + (7 << 14), nullptr, nullptr, nullptr, nullptr, out, 1);
    }
    k_epi2<<<(NN * 32 + 255) / 256, 256, 0, stream>>>(out, maskb, b2);
  }
}